// Round 7
// baseline (434.342 us; speedup 1.0000x reference)
//
#include <hip/hip_runtime.h>
#include <hip/hip_bf16.h>
#include <math.h>

#define D_MODEL 1024
#define D_HIDDEN 4096
#define N_EXP 8
#define N_TOK 4096

typedef __attribute__((ext_vector_type(8))) __bf16 bf16x8_t;
typedef __attribute__((ext_vector_type(4))) float f32x4_t;

// ---- workspace layout (bytes) ----
// counts @0 (32B), prefix @128 (36B), bucket @256 (128KB)
// xb  @256K           : 8 MB   (fp32-fallback only)
// HT  @256K+8M        : 42 MB  (bucket-tiled h chunks; fallback row-major h)
// W1T @256K+50M       : 64 MB  (tiled W1 bf16)
// W2T @256K+114M      : 64 MB  (tiled W2 bf16)
// AE  @256K+178M      : 10.5MB (bucket-tiled x bf16)
#define WS_PREFIX_OFF 128
#define WS_BUCKET_OFF 256
#define WS_XB_OFF     ((size_t)1 << 18)
#define WS_HT_OFF     (((size_t)1 << 18) + ((size_t)8 << 20))
#define WS_W1T_OFF    (((size_t)1 << 18) + ((size_t)50 << 20))
#define WS_W2T_OFF    (((size_t)1 << 18) + ((size_t)114 << 20))
#define WS_AE_OFF     (((size_t)1 << 18) + ((size_t)178 << 20))
#define WS_NEED       (((size_t)1 << 18) + ((size_t)189 << 20))
#define WS_NEED_FB    (((size_t)1 << 18) + ((size_t)40 << 20))

__device__ __forceinline__ void gload16(const void* g, void* l) {
    __builtin_amdgcn_global_load_lds(
        (__attribute__((address_space(1))) void*)(g),
        (__attribute__((address_space(3))) void*)(l),
        16, 0, 0);
}

template<int N> __device__ __forceinline__ void waitcnt_vm() {
    if constexpr (N >= 8)      asm volatile("s_waitcnt vmcnt(8)" ::: "memory");
    else if constexpr (N == 6) asm volatile("s_waitcnt vmcnt(6)" ::: "memory");
    else if constexpr (N == 4) asm volatile("s_waitcnt vmcnt(4)" ::: "memory");
    else                       asm volatile("s_waitcnt vmcnt(0)" ::: "memory");
}

__global__ __launch_bounds__(64) void init_counts(int* counts) {
    if (threadIdx.x < N_EXP) counts[threadIdx.x] = 0;
}

__global__ __launch_bounds__(64) void prefix_kernel(const int* counts, int* prefix) {
    if (threadIdx.x == 0) {
        int s = 0;
#pragma unroll
        for (int e = 0; e < N_EXP; ++e) { prefix[e] = s; s += (counts[e] + 127) >> 7; }
    }
}

// Router: one wave per token, fp64 logit accumulation; also emits xb (fallback).
__global__ __launch_bounds__(256) void router_kernel(
    const float* __restrict__ x, const float* __restrict__ Wg,
    const float* __restrict__ bg, int* __restrict__ counts,
    int* __restrict__ bucket, __hip_bfloat16* __restrict__ xb)
{
    const int wid  = threadIdx.x >> 6;
    const int lane = threadIdx.x & 63;
    const int t    = blockIdx.x * 4 + wid;
    const float* xr = x + (size_t)t * D_MODEL;

    double acc[N_EXP];
#pragma unroll
    for (int e = 0; e < N_EXP; ++e) acc[e] = 0.0;

#pragma unroll
    for (int j = 0; j < D_MODEL / 64; ++j) {
        const int d = j * 64 + lane;
        const float xv = xr[d];
        xb[(size_t)t * D_MODEL + d] = __float2bfloat16(xv);
        const float4* wr = (const float4*)(Wg + (size_t)d * N_EXP);
        const float4 w0 = wr[0], w1 = wr[1];
        const double xd = (double)xv;
        acc[0] += xd * (double)w0.x; acc[1] += xd * (double)w0.y;
        acc[2] += xd * (double)w0.z; acc[3] += xd * (double)w0.w;
        acc[4] += xd * (double)w1.x; acc[5] += xd * (double)w1.y;
        acc[6] += xd * (double)w1.z; acc[7] += xd * (double)w1.w;
    }
#pragma unroll
    for (int e = 0; e < N_EXP; ++e) {
        double v = acc[e];
#pragma unroll
        for (int off = 32; off >= 1; off >>= 1) v += __shfl_xor(v, off, 64);
        acc[e] = v + (double)bg[e];
    }
    if (lane == 0) {
        int best = 0; double bv = acc[0];
#pragma unroll
        for (int e = 1; e < N_EXP; ++e)
            if (acc[e] > bv) { bv = acc[e]; best = e; }
        const int pos = atomicAdd(&counts[best], 1);
        bucket[best * N_TOK + pos] = t;
    }
}

// ---- W1 fp32 [e][k][4096] -> tiled chunks [e][nblk 32][kc 16][n 128][slot^ 8][16B]
__global__ __launch_bounds__(256) void convert_w1(
    const float* __restrict__ W, __hip_bfloat16* __restrict__ Wt)
{
    const int nblk = blockIdx.x, kc = blockIdx.y, e = blockIdx.z;
    const int k0 = kc * 64, n0 = nblk * 128;
    const int tid = threadIdx.x;
    __shared__ __hip_bfloat16 Lt[128 * 72];   // [n][k], row stride 144B

    const int kr = tid >> 2;                  // 0..63
    const int cq = tid & 3;                   // col group of 32
    const float* src = W + (size_t)e * D_MODEL * D_HIDDEN + (size_t)(k0 + kr) * D_HIDDEN + n0 + cq * 32;
#pragma unroll
    for (int f = 0; f < 8; ++f) {
        const float4 v = *(const float4*)(src + f * 4);
#pragma unroll
        for (int j = 0; j < 4; ++j) {
            const int n = cq * 32 + f * 4 + j;
            *(__hip_bfloat16*)((char*)Lt + (size_t)n * 144 + kr * 2) = __float2bfloat16(((const float*)&v)[j]);
        }
    }
    __syncthreads();

    char* outc = (char*)Wt + (((size_t)e * 32 + nblk) * 16 + kc) * 16384;
    const int n = tid >> 1, half = tid & 1;
#pragma unroll
    for (int s = 0; s < 4; ++s) {
        const int slot = half * 4 + s;
        const int ko = slot ^ (n & 7);
        const uint4 v = *(const uint4*)((const char*)Lt + (size_t)n * 144 + ko * 16);
        *(uint4*)(outc + (size_t)n * 128 + slot * 16) = v;
    }
}

// ---- W2 fp32 [e][k][1024] -> tiled chunks [e][nblk 16][kc 64][n 64][slot^ 8][16B]
__global__ __launch_bounds__(256) void convert_w2(
    const float* __restrict__ W, __hip_bfloat16* __restrict__ Wt)
{
    const int nblk = blockIdx.x, kc = blockIdx.y, e = blockIdx.z;
    const int k0 = kc * 64, n0 = nblk * 64;
    const int tid = threadIdx.x;
    __shared__ __hip_bfloat16 Lt[64 * 72];

    const int kr = tid >> 2;
    const int cq = tid & 3;                   // col group of 16
    const float* src = W + (size_t)e * D_HIDDEN * D_MODEL + (size_t)(k0 + kr) * D_MODEL + n0 + cq * 16;
#pragma unroll
    for (int f = 0; f < 4; ++f) {
        const float4 v = *(const float4*)(src + f * 4);
#pragma unroll
        for (int j = 0; j < 4; ++j) {
            const int n = cq * 16 + f * 4 + j;
            *(__hip_bfloat16*)((char*)Lt + (size_t)n * 144 + kr * 2) = __float2bfloat16(((const float*)&v)[j]);
        }
    }
    __syncthreads();

    char* outc = (char*)Wt + (((size_t)e * 16 + nblk) * 64 + kc) * 8192;
    const int n = tid >> 2, q = tid & 3;
#pragma unroll
    for (int s = 0; s < 2; ++s) {
        const int slot = q * 2 + s;
        const int ko = slot ^ (n & 7);
        const uint4 v = *(const uint4*)((const char*)Lt + (size_t)n * 144 + ko * 16);
        *(uint4*)(outc + (size_t)n * 128 + slot * 16) = v;
    }
}

// ---- gather x rows by bucket into tiled A chunks [mbg][kc 16][m 128][slot^ 8][16B]
__global__ __launch_bounds__(256) void gather_a(
    const float* __restrict__ x, const int* __restrict__ counts,
    const int* __restrict__ prefix, const int* __restrict__ bucket,
    __hip_bfloat16* __restrict__ Ae)
{
    const int mblk = blockIdx.x, kc = blockIdx.y, e = blockIdx.z;
    const int cnt = counts[e];
    if (mblk * 128 >= cnt) return;
    const int mbg = prefix[e] + mblk;
    const int tid = threadIdx.x;
    const int m = tid >> 1, half = tid & 1;
    int idx = mblk * 128 + m;
    if (idx >= cnt) idx = cnt - 1;
    const int tok = bucket[e * N_TOK + idx];
    const float* src = x + (size_t)tok * D_MODEL + kc * 64 + half * 32;
    char* dst = (char*)Ae + ((size_t)mbg * 16 + kc) * 16384 + (size_t)m * 128;
#pragma unroll
    for (int s = 0; s < 4; ++s) {
        const float4 a = *(const float4*)(src + s * 8);
        const float4 b = *(const float4*)(src + s * 8 + 4);
        union { __hip_bfloat16 hh[8]; uint4 u; } pk;
#pragma unroll
        for (int j = 0; j < 4; ++j) {
            pk.hh[j]     = __float2bfloat16(((const float*)&a)[j]);
            pk.hh[j + 4] = __float2bfloat16(((const float*)&b)[j]);
        }
        const int ko = half * 4 + s;
        *(uint4*)(dst + ((ko ^ (m & 7)) << 4)) = pk.u;
    }
}

// ============ tiled grouped GEMM: contiguous staging, counted-vmcnt dbuf ======
// A chunks (Ae / h_t) indexed by prefix[e]+mblk; B chunks by (e,nblk,kc).
// Every global_load_lds reads 1KB CONTIGUOUS (src offset == LDS offset + lane*16).
template<int K_TOT, int N_TOT, int BN, bool IS_FFN1>
__global__ __launch_bounds__(256) void ffn_gemm_t(
    const __hip_bfloat16* __restrict__ At,
    const __hip_bfloat16* __restrict__ Wt,
    const float* __restrict__ bias,
    const int* __restrict__ counts,
    const int* __restrict__ prefix,
    const int* __restrict__ bucket,
    __hip_bfloat16* __restrict__ hout,   // tiled h chunks (FFN1)
    float* __restrict__ yout)            // out (FFN2)
{
    constexpr int NG  = BN / 32;
    constexpr int NBI = BN / 32;             // B gload16 per wave per step
    constexpr int NB  = N_TOT / BN;
    constexpr int MB  = N_TOK / 128;
    constexpr int NWG = NB * MB * N_EXP;
    constexpr int KC  = K_TOT / 64;
    constexpr int ACH = 16384;               // A chunk bytes
    constexpr int BCH = BN * 128;            // B chunk bytes
    constexpr int ASZ = 16384;               // LDS A buffer
    constexpr int BSZ = BN * 128;            // LDS B buffer
    constexpr int L   = 4 + NBI;

    const int orig = blockIdx.x;
    const int wg   = (orig & 7) * (NWG >> 3) + (orig >> 3);
    const int e    = wg / (NB * MB);
    const int rem  = wg % (NB * MB);
    const int nblk = rem / MB;
    const int mblk = rem % MB;
    const int cnt  = counts[e];
    const int m0   = mblk * 128;
    if (m0 >= cnt) return;
    const int mbg  = prefix[e] + mblk;
    const int n0   = nblk * BN;

    const int tid  = threadIdx.x;
    const int lane = tid & 63;
    const int wid  = tid >> 6;
    const int wm   = wid >> 1, wn = wid & 1;

    __shared__ char As[2 * ASZ];
    __shared__ char Bs[2 * BSZ];
    __shared__ int s_tok[128];

    if (!IS_FFN1 && tid < 128) {
        int idx = m0 + tid;
        if (idx >= cnt) idx = cnt - 1;
        s_tok[tid] = bucket[e * N_TOK + idx];
    }

    const char* Abase = (const char*)At + (size_t)mbg * KC * ACH;
    const char* Bbase = (const char*)Wt + ((size_t)e * NB + nblk) * (size_t)KC * BCH;
    const int aoff = wid * 4096 + lane * 16;          // + i*1024
    const int boff = wid * (BCH / 4) + lane * 16;     // + i*1024

    f32x4_t acc[4][NG];
#pragma unroll
    for (int f = 0; f < 4; ++f)
#pragma unroll
        for (int g = 0; g < NG; ++g) acc[f][g] = (f32x4_t){0.f, 0.f, 0.f, 0.f};

    // ---- prologue: stage tile 0 into buf 0, drain once ----
#pragma unroll
    for (int i = 0; i < 4; ++i) gload16(Abase + aoff + i * 1024, As + (aoff - lane * 16) + i * 1024);
#pragma unroll
    for (int i = 0; i < NBI; ++i) gload16(Bbase + boff + i * 1024, Bs + (boff - lane * 16) + i * 1024);
    waitcnt_vm<0>();
    __builtin_amdgcn_s_barrier();

    for (int t = 0; t < KC; ++t) {
        const int c = t & 1;
        if (t + 1 < KC) {
            const char* An = Abase + (size_t)(t + 1) * ACH;
            const char* Bn = Bbase + (size_t)(t + 1) * BCH;
            char* lan = As + (c ^ 1) * ASZ + (aoff - lane * 16);
            char* lbn = Bs + (c ^ 1) * BSZ + (boff - lane * 16);
#pragma unroll
            for (int i = 0; i < 4; ++i) gload16(An + aoff + i * 1024, lan + i * 1024);
#pragma unroll
            for (int i = 0; i < NBI; ++i) gload16(Bn + boff + i * 1024, lbn + i * 1024);
            waitcnt_vm<L>();
        } else {
            waitcnt_vm<0>();
        }
        __builtin_amdgcn_s_barrier();
        __builtin_amdgcn_sched_barrier(0);

        const char* asb = As + c * ASZ;
        const char* bsb = Bs + c * BSZ;
#pragma unroll
        for (int kk = 0; kk < 2; ++kk) {
            uint4 af[4], bf[NG];
            const int ko = kk * 4 + (lane >> 4);
#pragma unroll
            for (int f = 0; f < 4; ++f) {
                const int r = wm * 64 + f * 16 + (lane & 15);
                af[f] = *(const uint4*)(asb + r * 128 + ((ko ^ (r & 7)) << 4));
            }
#pragma unroll
            for (int g = 0; g < NG; ++g) {
                const int n = wn * (BN / 2) + g * 16 + (lane & 15);
                bf[g] = *(const uint4*)(bsb + n * 128 + ((ko ^ (n & 7)) << 4));
            }
#pragma unroll
            for (int f = 0; f < 4; ++f)
#pragma unroll
                for (int g = 0; g < NG; ++g)
                    acc[f][g] = __builtin_amdgcn_mfma_f32_16x16x32_bf16(
                        __builtin_bit_cast(bf16x8_t, af[f]),
                        __builtin_bit_cast(bf16x8_t, bf[g]),
                        acc[f][g], 0, 0, 0);
        }
        __builtin_amdgcn_s_barrier();
    }

    // ---- epilogue ----
    if (IS_FFN1) {
        // write gelu(acc+bias) into tiled h chunks (bucket order, pads included)
        char* hb = (char*)hout + (size_t)mbg * (D_HIDDEN / 64) * 16384;
#pragma unroll
        for (int f = 0; f < 4; ++f) {
#pragma unroll
            for (int j = 0; j < 4; ++j) {
                const int m = wm * 64 + f * 16 + (lane >> 4) * 4 + j;
#pragma unroll
                for (int g = 0; g < NG; ++g) {
                    const int col = n0 + wn * (BN / 2) + g * 16 + (lane & 15);
                    float v = acc[f][g][j] + bias[e * N_TOT + col];
                    v = 0.5f * v * (1.0f + erff(v * 0.70710678118654752f));
                    const int kc = col >> 6, kw = col & 63, ko = kw >> 3, b = kw & 7;
                    *(__hip_bfloat16*)(hb + ((size_t)kc * 128 + m) * 128 +
                                       (((ko ^ (m & 7)) << 4) + (b << 1))) = __float2bfloat16(v);
                }
            }
        }
    } else {
#pragma unroll
        for (int f = 0; f < 4; ++f) {
#pragma unroll
            for (int j = 0; j < 4; ++j) {
                const int rl = wm * 64 + f * 16 + (lane >> 4) * 4 + j;
                const bool ok = (m0 + rl) < cnt;
                const int tok = s_tok[rl];
#pragma unroll
                for (int g = 0; g < NG; ++g) {
                    const int col = n0 + wn * (BN / 2) + g * 16 + (lane & 15);
                    const float v = acc[f][g][j] + bias[e * N_TOT + col];
                    if (ok) yout[(size_t)tok * N_TOT + col] = v;
                }
            }
        }
    }
}

// ===================== fp32-W fallback (used if ws too small) =================
template<int K_TOT, int N_TOT, bool IS_FFN1>
__global__ __launch_bounds__(256, 2) void ffn_gemm_f32(
    const __hip_bfloat16* __restrict__ A,
    const float* __restrict__ W,
    const float* __restrict__ bias,
    const int* __restrict__ counts,
    const int* __restrict__ bucket,
    __hip_bfloat16* __restrict__ hout,
    float* __restrict__ yout)
{
    const int e   = blockIdx.z;
    const int cnt = counts[e];
    const int m0  = blockIdx.y * 128;
    if (m0 >= cnt) return;
    const int n0   = blockIdx.x * 128;
    const int tid  = threadIdx.x;
    const int lane = tid & 63;
    const int wid  = tid >> 6;
    const int wm   = wid >> 1, wn = wid & 1;

    __shared__ __hip_bfloat16 As[128 * 64];
    __shared__ __hip_bfloat16 Bs[128 * 64];
    __shared__ int s_tok[128];

    if (tid < 128) {
        int idx = m0 + tid;
        if (idx >= cnt) idx = cnt - 1;
        s_tok[tid] = bucket[e * N_TOK + idx];
    }
    __syncthreads();

    const __hip_bfloat16* gA[4]; char* lA[4];
#pragma unroll
    for (int i = 0; i < 4; ++i) {
        const int r = wid * 32 + i * 8 + (lane >> 3);
        gA[i] = A + (size_t)s_tok[r] * K_TOT + (((lane & 7) ^ (r & 7)) << 3);
        lA[i] = (char*)As + (size_t)(wid * 32 + i * 8) * 128;
    }
    const int ko_t = lane & 7;
    const int nq   = wid * 8 + (lane >> 3);
    const float* wb = W + (size_t)e * K_TOT * N_TOT + (size_t)(ko_t * 8) * N_TOT + n0 + nq * 4;

    f32x4_t acc[4][4];
#pragma unroll
    for (int f = 0; f < 4; ++f)
#pragma unroll
        for (int g = 0; g < 4; ++g) acc[f][g] = (f32x4_t){0.f, 0.f, 0.f, 0.f};

    for (int k0 = 0; k0 < K_TOT; k0 += 64) {
#pragma unroll
        for (int i = 0; i < 4; ++i) gload16(gA[i] + k0, lA[i]);
        const float* wk = wb + (size_t)k0 * N_TOT;
        float4 v[8];
#pragma unroll
        for (int j = 0; j < 8; ++j) v[j] = *(const float4*)(wk + (size_t)j * N_TOT);
#pragma unroll
        for (int i = 0; i < 4; ++i) {
            const int n = nq * 4 + i;
            union { __hip_bfloat16 hh[8]; uint4 u; } pk;
#pragma unroll
            for (int j = 0; j < 8; ++j) pk.hh[j] = __float2bfloat16(((const float*)&v[j])[i]);
            *(uint4*)((char*)Bs + n * 128 + ((ko_t ^ (n & 7)) << 4)) = pk.u;
        }
        __syncthreads();

#pragma unroll
        for (int kk = 0; kk < 2; ++kk) {
            uint4 af[4], bf[4];
            const int ko = kk * 4 + (lane >> 4);
#pragma unroll
            for (int f = 0; f < 4; ++f) {
                const int r = wm * 64 + f * 16 + (lane & 15);
                af[f] = *(const uint4*)((const char*)As + r * 128 + ((ko ^ (r & 7)) << 4));
            }
#pragma unroll
            for (int g = 0; g < 4; ++g) {
                const int n = wn * 64 + g * 16 + (lane & 15);
                bf[g] = *(const uint4*)((const char*)Bs + n * 128 + ((ko ^ (n & 7)) << 4));
            }
#pragma unroll
            for (int f = 0; f < 4; ++f)
#pragma unroll
                for (int g = 0; g < 4; ++g)
                    acc[f][g] = __builtin_amdgcn_mfma_f32_16x16x32_bf16(
                        __builtin_bit_cast(bf16x8_t, af[f]),
                        __builtin_bit_cast(bf16x8_t, bf[g]),
                        acc[f][g], 0, 0, 0);
        }
        __syncthreads();
    }

#pragma unroll
    for (int f = 0; f < 4; ++f) {
#pragma unroll
        for (int j = 0; j < 4; ++j) {
            const int rl = wm * 64 + f * 16 + (lane >> 4) * 4 + j;
            const bool ok = (m0 + rl) < cnt;
            const int tok = s_tok[rl];
#pragma unroll
            for (int g = 0; g < 4; ++g) {
                const int col = n0 + wn * 64 + g * 16 + (lane & 15);
                float v = acc[f][g][j] + bias[e * N_TOT + col];
                if (IS_FFN1) {
                    v = 0.5f * v * (1.0f + erff(v * 0.70710678118654752f));
                    if (ok) hout[(size_t)tok * N_TOT + col] = __float2bfloat16(v);
                } else {
                    if (ok) yout[(size_t)tok * N_TOT + col] = v;
                }
            }
        }
    }
}

extern "C" void kernel_launch(void* const* d_in, const int* in_sizes, int n_in,
                              void* d_out, int out_size, void* d_ws, size_t ws_size,
                              hipStream_t stream) {
    const float* x  = (const float*)d_in[0];
    const float* Wg = (const float*)d_in[1];
    const float* bg = (const float*)d_in[2];
    const float* W1 = (const float*)d_in[3];
    const float* b1 = (const float*)d_in[4];
    const float* W2 = (const float*)d_in[5];
    const float* b2 = (const float*)d_in[6];
    float* out = (float*)d_out;

    char* ws = (char*)d_ws;
    int* counts = (int*)(ws);
    int* prefix = (int*)(ws + WS_PREFIX_OFF);
    int* bucket = (int*)(ws + WS_BUCKET_OFF);
    __hip_bfloat16* xb  = (__hip_bfloat16*)(ws + WS_XB_OFF);
    __hip_bfloat16* ht  = (__hip_bfloat16*)(ws + WS_HT_OFF);
    __hip_bfloat16* w1t = (__hip_bfloat16*)(ws + WS_W1T_OFF);
    __hip_bfloat16* w2t = (__hip_bfloat16*)(ws + WS_W2T_OFF);
    __hip_bfloat16* ae  = (__hip_bfloat16*)(ws + WS_AE_OFF);

    init_counts<<<dim3(1), dim3(64), 0, stream>>>(counts);
    router_kernel<<<dim3(N_TOK / 4), dim3(256), 0, stream>>>(x, Wg, bg, counts, bucket, xb);
    prefix_kernel<<<dim3(1), dim3(64), 0, stream>>>(counts, prefix);

    if (ws_size >= WS_NEED) {
        convert_w1<<<dim3(32, 16, N_EXP), dim3(256), 0, stream>>>(W1, w1t);
        convert_w2<<<dim3(16, 64, N_EXP), dim3(256), 0, stream>>>(W2, w2t);
        gather_a<<<dim3(32, 16, N_EXP), dim3(256), 0, stream>>>(x, counts, prefix, bucket, ae);
        // FFN1: N=4096, K=1024, BN=128
        ffn_gemm_t<D_MODEL, D_HIDDEN, 128, true>
            <<<dim3((D_HIDDEN / 128) * (N_TOK / 128) * N_EXP), dim3(256), 0, stream>>>(
                ae, w1t, b1, counts, prefix, bucket, ht, nullptr);
        // FFN2: N=1024, K=4096, BN=64
        ffn_gemm_t<D_HIDDEN, D_MODEL, 64, false>
            <<<dim3((D_MODEL / 64) * (N_TOK / 128) * N_EXP), dim3(256), 0, stream>>>(
                ht, w2t, b2, counts, prefix, bucket, nullptr, out);
    } else {
        __hip_bfloat16* h = ht;   // row-major in fallback
        ffn_gemm_f32<D_MODEL, D_HIDDEN, true>
            <<<dim3(D_HIDDEN / 128, N_TOK / 128, N_EXP), dim3(256), 0, stream>>>(
                xb, W1, b1, counts, bucket, h, nullptr);
        ffn_gemm_f32<D_HIDDEN, D_MODEL, false>
            <<<dim3(D_MODEL / 128, N_TOK / 128, N_EXP), dim3(256), 0, stream>>>(
                h, W2, b2, counts, bucket, nullptr, out);
    }
}

// Round 8
// 321.728 us; speedup vs baseline: 1.3500x; 1.3500x over previous
//
#include <hip/hip_runtime.h>
#include <hip/hip_bf16.h>
#include <math.h>

#define D_MODEL 1024
#define D_HIDDEN 4096
#define N_EXP 8
#define N_TOK 4096
#define MBS 40   // max 128-row m-slots: sum ceil(cnt_e/128) <= 32+7 = 39

typedef __attribute__((ext_vector_type(8))) __bf16 bf16x8_t;
typedef __attribute__((ext_vector_type(4))) float f32x4_t;

// ---- workspace layout (bytes) ----
// counts @0, prefix @128 (9 ints), bucket @256 (128KB)
// xb  @256K        : 8 MB    (fallback only)
// HT  @256K+8M     : 40 MB   (tiled h chunks [mbg][kc64][128m][slot^8][16B])
// W1T @256K+50M    : 64 MB   ([e][nblk32][kc16][128n][slot^8][16B])
// W2T @256K+114M   : 64 MB   ([e][nblk8][kc64][128n][slot^8][16B])
// AE  @256K+178M   : 10 MB   ([mbg][kc16][128m][slot^8][16B])
#define WS_PREFIX_OFF 128
#define WS_BUCKET_OFF 256
#define WS_XB_OFF     ((size_t)1 << 18)
#define WS_HT_OFF     (((size_t)1 << 18) + ((size_t)8 << 20))
#define WS_W1T_OFF    (((size_t)1 << 18) + ((size_t)50 << 20))
#define WS_W2T_OFF    (((size_t)1 << 18) + ((size_t)114 << 20))
#define WS_AE_OFF     (((size_t)1 << 18) + ((size_t)178 << 20))
#define WS_NEED       (((size_t)1 << 18) + ((size_t)189 << 20))

__device__ __forceinline__ void gload16(const void* g, void* l) {
    __builtin_amdgcn_global_load_lds(
        (__attribute__((address_space(1))) void*)(g),
        (__attribute__((address_space(3))) void*)(l),
        16, 0, 0);
}

__global__ __launch_bounds__(64) void init_counts(int* counts) {
    if (threadIdx.x < N_EXP) counts[threadIdx.x] = 0;
}

__global__ __launch_bounds__(64) void prefix_kernel(const int* counts, int* prefix) {
    if (threadIdx.x == 0) {
        int s = 0;
        prefix[0] = 0;
#pragma unroll
        for (int e = 0; e < N_EXP; ++e) { s += (counts[e] + 127) >> 7; prefix[e + 1] = s; }
    }
}

// Router: one wave per token, fp64 logit accumulation; also emits xb (fallback).
__global__ __launch_bounds__(256) void router_kernel(
    const float* __restrict__ x, const float* __restrict__ Wg,
    const float* __restrict__ bg, int* __restrict__ counts,
    int* __restrict__ bucket, __hip_bfloat16* __restrict__ xb)
{
    const int wid  = threadIdx.x >> 6;
    const int lane = threadIdx.x & 63;
    const int t    = blockIdx.x * 4 + wid;
    const float* xr = x + (size_t)t * D_MODEL;

    double acc[N_EXP];
#pragma unroll
    for (int e = 0; e < N_EXP; ++e) acc[e] = 0.0;

#pragma unroll
    for (int j = 0; j < D_MODEL / 64; ++j) {
        const int d = j * 64 + lane;
        const float xv = xr[d];
        xb[(size_t)t * D_MODEL + d] = __float2bfloat16(xv);
        const float4* wr = (const float4*)(Wg + (size_t)d * N_EXP);
        const float4 w0 = wr[0], w1 = wr[1];
        const double xd = (double)xv;
        acc[0] += xd * (double)w0.x; acc[1] += xd * (double)w0.y;
        acc[2] += xd * (double)w0.z; acc[3] += xd * (double)w0.w;
        acc[4] += xd * (double)w1.x; acc[5] += xd * (double)w1.y;
        acc[6] += xd * (double)w1.z; acc[7] += xd * (double)w1.w;
    }
#pragma unroll
    for (int e = 0; e < N_EXP; ++e) {
        double v = acc[e];
#pragma unroll
        for (int off = 32; off >= 1; off >>= 1) v += __shfl_xor(v, off, 64);
        acc[e] = v + (double)bg[e];
    }
    if (lane == 0) {
        int best = 0; double bv = acc[0];
#pragma unroll
        for (int e = 1; e < N_EXP; ++e)
            if (acc[e] > bv) { bv = acc[e]; best = e; }
        const int pos = atomicAdd(&counts[best], 1);
        bucket[best * N_TOK + pos] = t;
    }
}

// W fp32 [e][k][NT] -> tiled chunks [e][nblk][kc][128n][slot^][16B] (16KB each)
template<int KT, int NT>
__global__ __launch_bounds__(256) void convert_w(
    const float* __restrict__ W, __hip_bfloat16* __restrict__ Wt)
{
    constexpr int NB = NT / 128, KC = KT / 64;
    const int nblk = blockIdx.x, kc = blockIdx.y, e = blockIdx.z;
    const int k0 = kc * 64, n0 = nblk * 128;
    const int tid = threadIdx.x;
    __shared__ __hip_bfloat16 Lt[128 * 72];   // [n][k], row stride 144B

    const int kr = tid >> 2;                  // 0..63
    const int cq = tid & 3;                   // 32-col group
    const float* src = W + (size_t)e * KT * NT + (size_t)(k0 + kr) * NT + n0 + cq * 32;
#pragma unroll
    for (int f = 0; f < 8; ++f) {
        const float4 v = *(const float4*)(src + f * 4);
#pragma unroll
        for (int j = 0; j < 4; ++j) {
            const int n = cq * 32 + f * 4 + j;
            *(__hip_bfloat16*)((char*)Lt + (size_t)n * 144 + kr * 2) = __float2bfloat16(((const float*)&v)[j]);
        }
    }
    __syncthreads();

    char* outc = (char*)Wt + (((size_t)e * NB + nblk) * KC + kc) * 16384;
    const int n = tid >> 1, half = tid & 1;
#pragma unroll
    for (int s = 0; s < 4; ++s) {
        const int slot = half * 4 + s;
        const int ko = slot ^ (n & 7);
        const uint4 v = *(const uint4*)((const char*)Lt + (size_t)n * 144 + ko * 16);
        *(uint4*)(outc + (size_t)n * 128 + slot * 16) = v;
    }
}

// gather x rows by bucket into tiled A chunks [mbg][kc][128m][slot^][16B]
__global__ __launch_bounds__(256) void gather_a(
    const float* __restrict__ x, const int* __restrict__ counts,
    const int* __restrict__ prefix, const int* __restrict__ bucket,
    __hip_bfloat16* __restrict__ Ae)
{
    const int mbg = blockIdx.x, kc = blockIdx.y;
    if (mbg >= prefix[8]) return;
    int e = 0;
#pragma unroll
    for (int q = 1; q < 8; ++q) if (mbg >= prefix[q]) e = q;
    const int cnt  = counts[e];
    const int mblk = mbg - prefix[e];
    const int tid  = threadIdx.x;
    const int m = tid >> 1, half = tid & 1;
    int idx = mblk * 128 + m;
    if (idx >= cnt) idx = cnt - 1;
    const int tok = bucket[e * N_TOK + idx];
    const float* src = x + (size_t)tok * D_MODEL + kc * 64 + half * 32;
    char* dst = (char*)Ae + ((size_t)mbg * 16 + kc) * 16384 + (size_t)m * 128;
#pragma unroll
    for (int s = 0; s < 4; ++s) {
        const float4 a = *(const float4*)(src + s * 8);
        const float4 b = *(const float4*)(src + s * 8 + 4);
        union { __hip_bfloat16 hh[8]; uint4 u; } pk;
#pragma unroll
        for (int j = 0; j < 4; ++j) {
            pk.hh[j]     = __float2bfloat16(((const float*)&a)[j]);
            pk.hh[j + 4] = __float2bfloat16(((const float*)&b)[j]);
        }
        const int ko = half * 4 + s;
        *(uint4*)(dst + ((ko ^ (m & 7)) << 4)) = pk.u;
    }
}

// ===== compact grouped GEMM: 128x128x64, single-buffer LDS, m97 structure =====
// grid = MBS * NB flat; nblk-major order (mbg fastest) + XCD-chunked swizzle:
// each XCD owns NB/8 B-panels and streams all m-slots through them (B L2-hot).
template<int K_TOT, int N_TOT, bool IS_FFN1>
__global__ __launch_bounds__(256, 4) void ffn_gemm_c(
    const __hip_bfloat16* __restrict__ At,
    const __hip_bfloat16* __restrict__ Wt,
    const float* __restrict__ bias,
    const int* __restrict__ counts,
    const int* __restrict__ prefix,
    const int* __restrict__ bucket,
    __hip_bfloat16* __restrict__ hout,   // tiled h chunks (FFN1)
    float* __restrict__ yout)            // out (FFN2)
{
    constexpr int NB  = N_TOT / 128;
    constexpr int KC  = K_TOT / 64;
    constexpr int NWG = MBS * NB;            // 1280 / 320, %8==0

    const int orig = blockIdx.x;
    const int wg   = (orig & 7) * (NWG >> 3) + (orig >> 3);
    const int nblk = wg / MBS;
    const int mbg  = wg % MBS;
    if (mbg >= prefix[8]) return;
    int e = 0;
#pragma unroll
    for (int q = 1; q < 8; ++q) if (mbg >= prefix[q]) e = q;
    const int cnt = counts[e];
    const int m0  = (mbg - prefix[e]) * 128;
    const int n0  = nblk * 128;

    const int tid  = threadIdx.x;
    const int lane = tid & 63;
    const int wid  = tid >> 6;
    const int wm   = wid >> 1, wn = wid & 1;

    __shared__ char As[16384];
    __shared__ char Bs[16384];
    __shared__ int s_tok[128];

    if (!IS_FFN1 && tid < 128) {
        int idx = m0 + tid;
        if (idx >= cnt) idx = cnt - 1;
        s_tok[tid] = bucket[e * N_TOK + idx];
    }

    const char* Abase = (const char*)At + (size_t)mbg * KC * 16384;
    const char* Bbase = (const char*)Wt + ((size_t)e * NB + nblk) * (size_t)KC * 16384;
    const int off  = wid * 4096 + lane * 16;   // src offset; LDS dest = off - lane*16
    char* lA = As + wid * 4096;
    char* lB = Bs + wid * 4096;

    f32x4_t acc[4][4];
#pragma unroll
    for (int f = 0; f < 4; ++f)
#pragma unroll
        for (int g = 0; g < 4; ++g) acc[f][g] = (f32x4_t){0.f, 0.f, 0.f, 0.f};

    for (int t = 0; t < KC; ++t) {
        const char* Ac = Abase + (size_t)t * 16384 + off;
        const char* Bc = Bbase + (size_t)t * 16384 + off;
#pragma unroll
        for (int i = 0; i < 4; ++i) gload16(Ac + i * 1024, lA + i * 1024);
#pragma unroll
        for (int i = 0; i < 4; ++i) gload16(Bc + i * 1024, lB + i * 1024);
        __syncthreads();   // drains vmcnt: tile ready

#pragma unroll
        for (int kk = 0; kk < 2; ++kk) {
            uint4 af[4], bf[4];
            const int ko = kk * 4 + (lane >> 4);
#pragma unroll
            for (int f = 0; f < 4; ++f) {
                const int r = wm * 64 + f * 16 + (lane & 15);
                af[f] = *(const uint4*)(As + r * 128 + ((ko ^ (r & 7)) << 4));
            }
#pragma unroll
            for (int g = 0; g < 4; ++g) {
                const int n = wn * 64 + g * 16 + (lane & 15);
                bf[g] = *(const uint4*)(Bs + n * 128 + ((ko ^ (n & 7)) << 4));
            }
#pragma unroll
            for (int f = 0; f < 4; ++f)
#pragma unroll
                for (int g = 0; g < 4; ++g)
                    acc[f][g] = __builtin_amdgcn_mfma_f32_16x16x32_bf16(
                        __builtin_bit_cast(bf16x8_t, af[f]),
                        __builtin_bit_cast(bf16x8_t, bf[g]),
                        acc[f][g], 0, 0, 0);
        }
        __syncthreads();   // all waves done with buffers
    }

    // ---- epilogue: C/D layout col=lane&15, row=(lane>>4)*4+j ----
    if (IS_FFN1) {
        char* hb = (char*)hout + (size_t)mbg * (D_HIDDEN / 64) * 16384;
#pragma unroll
        for (int f = 0; f < 4; ++f) {
#pragma unroll
            for (int j = 0; j < 4; ++j) {
                const int m = wm * 64 + f * 16 + (lane >> 4) * 4 + j;
#pragma unroll
                for (int g = 0; g < 4; ++g) {
                    const int col = n0 + wn * 64 + g * 16 + (lane & 15);
                    float v = acc[f][g][j] + bias[e * N_TOT + col];
                    v = 0.5f * v * (1.0f + erff(v * 0.70710678118654752f));
                    const int kc = col >> 6, kw = col & 63, ko = kw >> 3, b = kw & 7;
                    *(__hip_bfloat16*)(hb + ((size_t)kc * 128 + m) * 128 +
                                       (((ko ^ (m & 7)) << 4) + (b << 1))) = __float2bfloat16(v);
                }
            }
        }
    } else {
#pragma unroll
        for (int f = 0; f < 4; ++f) {
#pragma unroll
            for (int j = 0; j < 4; ++j) {
                const int rl = wm * 64 + f * 16 + (lane >> 4) * 4 + j;
                const bool ok = (m0 + rl) < cnt;
                const int tok = s_tok[rl];
#pragma unroll
                for (int g = 0; g < 4; ++g) {
                    const int col = n0 + wn * 64 + g * 16 + (lane & 15);
                    const float v = acc[f][g][j] + bias[e * N_TOT + col];
                    if (ok) yout[(size_t)tok * N_TOT + col] = v;
                }
            }
        }
    }
}

// ===================== fp32-W fallback (used if ws too small) =================
template<int K_TOT, int N_TOT, bool IS_FFN1>
__global__ __launch_bounds__(256, 2) void ffn_gemm_f32(
    const __hip_bfloat16* __restrict__ A,
    const float* __restrict__ W,
    const float* __restrict__ bias,
    const int* __restrict__ counts,
    const int* __restrict__ bucket,
    __hip_bfloat16* __restrict__ hout,
    float* __restrict__ yout)
{
    const int e   = blockIdx.z;
    const int cnt = counts[e];
    const int m0  = blockIdx.y * 128;
    if (m0 >= cnt) return;
    const int n0   = blockIdx.x * 128;
    const int tid  = threadIdx.x;
    const int lane = tid & 63;
    const int wid  = tid >> 6;
    const int wm   = wid >> 1, wn = wid & 1;

    __shared__ __hip_bfloat16 As[128 * 64];
    __shared__ __hip_bfloat16 Bs[128 * 64];
    __shared__ int s_tok[128];

    if (tid < 128) {
        int idx = m0 + tid;
        if (idx >= cnt) idx = cnt - 1;
        s_tok[tid] = bucket[e * N_TOK + idx];
    }
    __syncthreads();

    const __hip_bfloat16* gA[4]; char* lA[4];
#pragma unroll
    for (int i = 0; i < 4; ++i) {
        const int r = wid * 32 + i * 8 + (lane >> 3);
        gA[i] = A + (size_t)s_tok[r] * K_TOT + (((lane & 7) ^ (r & 7)) << 3);
        lA[i] = (char*)As + (size_t)(wid * 32 + i * 8) * 128;
    }
    const int ko_t = lane & 7;
    const int nq   = wid * 8 + (lane >> 3);
    const float* wb = W + (size_t)e * K_TOT * N_TOT + (size_t)(ko_t * 8) * N_TOT + n0 + nq * 4;

    f32x4_t acc[4][4];
#pragma unroll
    for (int f = 0; f < 4; ++f)
#pragma unroll
        for (int g = 0; g < 4; ++g) acc[f][g] = (f32x4_t){0.f, 0.f, 0.f, 0.f};

    for (int k0 = 0; k0 < K_TOT; k0 += 64) {
#pragma unroll
        for (int i = 0; i < 4; ++i) gload16(gA[i] + k0, lA[i]);
        const float* wk = wb + (size_t)k0 * N_TOT;
        float4 v[8];
#pragma unroll
        for (int j = 0; j < 8; ++j) v[j] = *(const float4*)(wk + (size_t)j * N_TOT);
#pragma unroll
        for (int i = 0; i < 4; ++i) {
            const int n = nq * 4 + i;
            union { __hip_bfloat16 hh[8]; uint4 u; } pk;
#pragma unroll
            for (int j = 0; j < 8; ++j) pk.hh[j] = __float2bfloat16(((const float*)&v[j])[i]);
            *(uint4*)((char*)Bs + n * 128 + ((ko_t ^ (n & 7)) << 4)) = pk.u;
        }
        __syncthreads();

#pragma unroll
        for (int kk = 0; kk < 2; ++kk) {
            uint4 af[4], bf[4];
            const int ko = kk * 4 + (lane >> 4);
#pragma unroll
            for (int f = 0; f < 4; ++f) {
                const int r = wm * 64 + f * 16 + (lane & 15);
                af[f] = *(const uint4*)((const char*)As + r * 128 + ((ko ^ (r & 7)) << 4));
            }
#pragma unroll
            for (int g = 0; g < 4; ++g) {
                const int n = wn * 64 + g * 16 + (lane & 15);
                bf[g] = *(const uint4*)((const char*)Bs + n * 128 + ((ko ^ (n & 7)) << 4));
            }
#pragma unroll
            for (int f = 0; f < 4; ++f)
#pragma unroll
                for (int g = 0; g < 4; ++g)
                    acc[f][g] = __builtin_amdgcn_mfma_f32_16x16x32_bf16(
                        __builtin_bit_cast(bf16x8_t, af[f]),
                        __builtin_bit_cast(bf16x8_t, bf[g]),
                        acc[f][g], 0, 0, 0);
        }
        __syncthreads();
    }

#pragma unroll
    for (int f = 0; f < 4; ++f) {
#pragma unroll
        for (int j = 0; j < 4; ++j) {
            const int rl = wm * 64 + f * 16 + (lane >> 4) * 4 + j;
            const bool ok = (m0 + rl) < cnt;
            const int tok = s_tok[rl];
#pragma unroll
            for (int g = 0; g < 4; ++g) {
                const int col = n0 + wn * 64 + g * 16 + (lane & 15);
                float v = acc[f][g][j] + bias[e * N_TOT + col];
                if (IS_FFN1) {
                    v = 0.5f * v * (1.0f + erff(v * 0.70710678118654752f));
                    if (ok) hout[(size_t)tok * N_TOT + col] = __float2bfloat16(v);
                } else {
                    if (ok) yout[(size_t)tok * N_TOT + col] = v;
                }
            }
        }
    }
}

extern "C" void kernel_launch(void* const* d_in, const int* in_sizes, int n_in,
                              void* d_out, int out_size, void* d_ws, size_t ws_size,
                              hipStream_t stream) {
    const float* x  = (const float*)d_in[0];
    const float* Wg = (const float*)d_in[1];
    const float* bg = (const float*)d_in[2];
    const float* W1 = (const float*)d_in[3];
    const float* b1 = (const float*)d_in[4];
    const float* W2 = (const float*)d_in[5];
    const float* b2 = (const float*)d_in[6];
    float* out = (float*)d_out;

    char* ws = (char*)d_ws;
    int* counts = (int*)(ws);
    int* prefix = (int*)(ws + WS_PREFIX_OFF);
    int* bucket = (int*)(ws + WS_BUCKET_OFF);
    __hip_bfloat16* xb  = (__hip_bfloat16*)(ws + WS_XB_OFF);
    __hip_bfloat16* ht  = (__hip_bfloat16*)(ws + WS_HT_OFF);
    __hip_bfloat16* w1t = (__hip_bfloat16*)(ws + WS_W1T_OFF);
    __hip_bfloat16* w2t = (__hip_bfloat16*)(ws + WS_W2T_OFF);
    __hip_bfloat16* ae  = (__hip_bfloat16*)(ws + WS_AE_OFF);

    init_counts<<<dim3(1), dim3(64), 0, stream>>>(counts);
    router_kernel<<<dim3(N_TOK / 4), dim3(256), 0, stream>>>(x, Wg, bg, counts, bucket, xb);
    prefix_kernel<<<dim3(1), dim3(64), 0, stream>>>(counts, prefix);

    if (ws_size >= WS_NEED) {
        convert_w<D_MODEL, D_HIDDEN><<<dim3(32, 16, N_EXP), dim3(256), 0, stream>>>(W1, w1t);
        convert_w<D_HIDDEN, D_MODEL><<<dim3(8, 64, N_EXP), dim3(256), 0, stream>>>(W2, w2t);
        gather_a<<<dim3(MBS, 16), dim3(256), 0, stream>>>(x, counts, prefix, bucket, ae);
        // FFN1: N=4096, K=1024 -> grid 40*32 = 1280
        ffn_gemm_c<D_MODEL, D_HIDDEN, true>
            <<<dim3(MBS * (D_HIDDEN / 128)), dim3(256), 0, stream>>>(
                ae, w1t, b1, counts, prefix, bucket, ht, nullptr);
        // FFN2: N=1024, K=4096 -> grid 40*8 = 320
        ffn_gemm_c<D_HIDDEN, D_MODEL, false>
            <<<dim3(MBS * (D_MODEL / 128)), dim3(256), 0, stream>>>(
                ht, w2t, b2, counts, prefix, bucket, nullptr, out);
    } else {
        __hip_bfloat16* h = ht;   // row-major in fallback
        ffn_gemm_f32<D_MODEL, D_HIDDEN, true>
            <<<dim3(D_HIDDEN / 128, N_TOK / 128, N_EXP), dim3(256), 0, stream>>>(
                xb, W1, b1, counts, bucket, h, nullptr);
        ffn_gemm_f32<D_HIDDEN, D_MODEL, false>
            <<<dim3(D_MODEL / 128, N_TOK / 128, N_EXP), dim3(256), 0, stream>>>(
                h, W2, b2, counts, bucket, nullptr, out);
    }
}